// Round 5
// baseline (199.510 us; speedup 1.0000x reference)
//
#include <hip/hip_runtime.h>
#include <hip/hip_bf16.h>
#include <cstdint>

#define DEVI __device__ __forceinline__

typedef __bf16 bf16x8 __attribute__((ext_vector_type(8)));
typedef float  f32x4  __attribute__((ext_vector_type(4)));

constexpr int Hdim = 1024;
constexpr int Vdim = 32000;
constexpr int Ldim = 512;
constexpr int Bdim = 256;

DEVI unsigned short f2bf(float f) {
  __bf16 h = (__bf16)f;                       // RNE
  return __builtin_bit_cast(unsigned short, h);
}

// ===========================================================================
// gemm_flat3: C[256 x 32000] = A[256x1024](bf16) @ W[32000x1024](f32)^T + bias
// High-occupancy latency-hiding version (R4 post-mortem: all low-occupancy
// schedules plateau at ~1.4 TB/s supply with ~95% idle pipes; TLP is the
// untried lever).
//   - N-tile 32, K-step 32. LDS = W tile only, double-buffered 2 x 2.3 KB
//     (PITCH 36 elems -> 2-way bank aliasing = free, m136).
//   - A fragments (bf16) load DIRECT to registers (each wave owns 64 rows,
//     no sharing -> no LDS needed). Ping-pong reg sets, static indices.
//   - One s_barrier per K-step; compiler-placed waitcnts (no manual asm).
//   - __launch_bounds__(256, 5) -> 5 blocks/CU, 20 waves/CU (62%).
//   - Grid 1000 blocks; W read exactly once machine-wide.
// MFMA 16x16x32_bf16; C/D: col=lane&15, row=(lane>>4)*4+reg (m89-verified).
// ===========================================================================
constexpr int FP = 36;               // LDS row pitch in bf16 elems

__global__ __launch_bounds__(256, 5)
void gemm_flat3(const unsigned short* __restrict__ A,
                const float* __restrict__ W,
                const float* __restrict__ bias,
                float* __restrict__ C,
                float2* __restrict__ plse)
{
  __shared__ unsigned short lW[2][32 * FP];

  const int t    = threadIdx.x;
  const int lane = t & 63;
  const int wv   = t >> 6;
  const int r16  = lane & 15;
  const int k8   = (lane >> 4) * 8;
  const int n0   = blockIdx.x * 32;

  const int srow = t >> 3;            // staging row 0..31
  const int stc  = (t & 7) * 4;       // staging k 0..28

  f32x4 acc[4][2];
#pragma unroll
  for (int m = 0; m < 4; ++m)
#pragma unroll
    for (int n = 0; n < 2; ++n)
#pragma unroll
      for (int r = 0; r < 4; ++r) acc[m][n][r] = 0.f;

  uint4 a0_[4], a1_[4];
  f32x4 w0_, w1_;

#define LOADW(RW, KT) \
    RW = *reinterpret_cast<const f32x4*>( \
        W + (size_t)(n0 + srow) * 1024 + (KT) * 32 + stc)

#define LOADA(ARR, KT) do {                                                    \
    const int ko_ = (KT) * 32 + k8;                                            \
    _Pragma("unroll")                                                          \
    for (int m = 0; m < 4; ++m)                                                \
      ARR[m] = *reinterpret_cast<const uint4*>(                                \
          A + (size_t)(wv * 64 + m * 16 + r16) * 1024 + ko_);                  \
  } while (0)

#define STOREW(RW, BUF) do {                                                   \
    ushort4 u_;                                                                \
    u_.x = f2bf(RW[0]); u_.y = f2bf(RW[1]);                                    \
    u_.z = f2bf(RW[2]); u_.w = f2bf(RW[3]);                                    \
    *reinterpret_cast<ushort4*>(&lW[BUF][srow * FP + stc]) = u_;               \
  } while (0)

#define COMP(ARR, BUF) do {                                                    \
    bf16x8 bw_[2];                                                             \
    _Pragma("unroll")                                                          \
    for (int n = 0; n < 2; ++n)                                                \
      bw_[n] = *reinterpret_cast<const bf16x8*>(                               \
          &lW[BUF][(n * 16 + r16) * FP + k8]);                                 \
    _Pragma("unroll")                                                          \
    for (int m = 0; m < 4; ++m)                                                \
      _Pragma("unroll")                                                        \
      for (int n = 0; n < 2; ++n)                                              \
        acc[m][n] = __builtin_amdgcn_mfma_f32_16x16x32_bf16(                   \
            __builtin_bit_cast(bf16x8, ARR[m]), bw_[n], acc[m][n], 0, 0, 0);   \
  } while (0)

  LOADW(w0_, 0); LOADA(a0_, 0);
  STOREW(w0_, 0);
  __syncthreads();

  for (int kt = 0; kt < 32; kt += 2) {
    // step kt: compute buf[0], stage kt+1 into buf[1]
    LOADW(w1_, kt + 1); LOADA(a1_, kt + 1);
    COMP(a0_, 0);
    STOREW(w1_, 1);
    __syncthreads();
    // step kt+1: compute buf[1], stage kt+2 into buf[0]
    { const int kn_ = (kt + 2 < 32) ? kt + 2 : 31;
      LOADW(w0_, kn_); LOADA(a0_, kn_); }
    COMP(a1_, 1);
    STOREW(w0_, 0);
    __syncthreads();
  }

#undef COMP
#undef STOREW
#undef LOADA
#undef LOADW

  // ---------------- epilogue: bias, store, LSE partials --------------------
#pragma unroll
  for (int n = 0; n < 2; ++n) {
    const int col = n0 + n * 16 + r16;
    const float bv = bias[col];
#pragma unroll
    for (int m = 0; m < 4; ++m) {
      const int rbase = wv * 64 + m * 16 + (lane >> 4) * 4;
#pragma unroll
      for (int r = 0; r < 4; ++r) {
        const float v = acc[m][n][r] + bv;
        acc[m][n][r] = v;
        C[(size_t)(rbase + r) * Vdim + col] = v;
      }
    }
  }
#pragma unroll
  for (int m = 0; m < 4; ++m) {
#pragma unroll
    for (int r = 0; r < 4; ++r) {
      float mx = fmaxf(acc[m][0][r], acc[m][1][r]);
#pragma unroll
      for (int o = 1; o < 16; o <<= 1) mx = fmaxf(mx, __shfl_xor(mx, o, 16));
      float s = __expf(acc[m][0][r] - mx) + __expf(acc[m][1][r] - mx);
#pragma unroll
      for (int o = 1; o < 16; o <<= 1) s += __shfl_xor(s, o, 16);
      if (r16 == 0) {
        const int row = wv * 64 + m * 16 + (lane >> 4) * 4 + r;
        plse[(size_t)row * gridDim.x + blockIdx.x] = make_float2(mx, s);
      }
    }
  }
}

// ---------------------------------------------------------------------------
// Small-GEMM engine: reg-staged dbuf, split-K atomics (bias pre-initialized)
// ---------------------------------------------------------------------------
template<int WM, bool ABF16, bool DUAL>
__global__ __launch_bounds__(256, 2)
void gemm_bt(const void* __restrict__ Av0, const float* __restrict__ Wt0,
             const void* __restrict__ Av1, const float* __restrict__ Wt1,
             const float* __restrict__ bias,
             float* __restrict__ C0, float* __restrict__ C1,
             int K, int ldc, int col_off, int act, int aact0,
             int nsplit)
{
  constexpr int MT    = 4 * WM;
  constexpr int PITCH = 40;
  constexpr int ITA   = MT / 32;
  constexpr int MR    = WM / 16;

  __shared__ unsigned short lA[2 * MT * PITCH];
  __shared__ unsigned short lW[2 * 64 * PITCH];

  const int t  = threadIdx.x;
  const int m0 = blockIdx.y * MT;
  const int n0 = blockIdx.x * 64;

  int kz = blockIdx.z, half = 0;
  if (DUAL) { half = (kz >= nsplit) ? 1 : 0; kz -= half * nsplit; }
  const int NK = K / (32 * nsplit);
  const int kb = kz * NK;

  const void*  Av = (DUAL && half) ? Av1 : Av0;
  const float* Wt = (DUAL && half) ? Wt1 : Wt0;
  float*       C  = (DUAL && half) ? C1  : C0;
  const int  aact = (DUAL && half) ? 0 : aact0;

  const int tr = t >> 3;
  const int tc = (t & 7) * 4;

  const float*          Af = ABF16 ? nullptr : ((const float*)Av) + (size_t)m0 * K;
  const unsigned short* Ab = ABF16 ? ((const unsigned short*)Av) + (size_t)m0 * K : nullptr;
  const float*          Wb = Wt + (size_t)n0 * K;

  const int lane = t & 63;
  const int wv   = t >> 6;
  const int r16  = lane & 15;
  const int k8   = (lane >> 4) * 8;

  f32x4 acc[MR][4];
#pragma unroll
  for (int m = 0; m < MR; ++m)
#pragma unroll
    for (int n = 0; n < 4; ++n)
#pragma unroll
      for (int r = 0; r < 4; ++r) acc[m][n][r] = 0.f;

  struct RS { f32x4 ra[ITA]; ushort4 rab[ITA]; f32x4 rw[2]; };

  auto loadT = [&](RS& rg, int kt) {
    const int ko = (kb + kt) * 32 + tc;
    if constexpr (ABF16) {
      const unsigned short* ap = Ab + ko;
#pragma unroll
      for (int i = 0; i < ITA; ++i)
        rg.rab[i] = *reinterpret_cast<const ushort4*>(ap + (size_t)(tr + 32 * i) * K);
    } else {
      const float* ap = Af + ko;
#pragma unroll
      for (int i = 0; i < ITA; ++i)
        rg.ra[i] = *reinterpret_cast<const f32x4*>(ap + (size_t)(tr + 32 * i) * K);
    }
    const float* wp = Wb + ko;
#pragma unroll
    for (int i = 0; i < 2; ++i)
      rg.rw[i] = *reinterpret_cast<const f32x4*>(wp + (size_t)(tr + 32 * i) * K);
  };

  auto storeT = [&](RS& rg, int bo) {
    unsigned short* sA = &lA[bo * MT * PITCH];
    unsigned short* sW = &lW[bo * 64 * PITCH];
#pragma unroll
    for (int i = 0; i < ITA; ++i) {
      ushort4 u;
      if constexpr (ABF16) u = rg.rab[i];
      else {
        f32x4 v = rg.ra[i];
        if (aact) { v[0]=fmaxf(v[0],0.f); v[1]=fmaxf(v[1],0.f);
                    v[2]=fmaxf(v[2],0.f); v[3]=fmaxf(v[3],0.f); }
        u.x = f2bf(v[0]); u.y = f2bf(v[1]); u.z = f2bf(v[2]); u.w = f2bf(v[3]);
      }
      *reinterpret_cast<ushort4*>(&sA[(tr + 32 * i) * PITCH + tc]) = u;
    }
#pragma unroll
    for (int i = 0; i < 2; ++i) {
      f32x4 v = rg.rw[i]; ushort4 u;
      u.x = f2bf(v[0]); u.y = f2bf(v[1]); u.z = f2bf(v[2]); u.w = f2bf(v[3]);
      *reinterpret_cast<ushort4*>(&sW[(tr + 32 * i) * PITCH + tc]) = u;
    }
  };

  auto comp = [&](int bo) {
    const unsigned short* sA = &lA[bo * MT * PITCH];
    const unsigned short* sW = &lW[bo * 64 * PITCH];
    bf16x8 af[MR], bfr[4];
#pragma unroll
    for (int m = 0; m < MR; ++m)
      af[m] = *reinterpret_cast<const bf16x8*>(&sA[(wv * WM + m * 16 + r16) * PITCH + k8]);
#pragma unroll
    for (int n = 0; n < 4; ++n)
      bfr[n] = *reinterpret_cast<const bf16x8*>(&sW[(n * 16 + r16) * PITCH + k8]);
#pragma unroll
    for (int m = 0; m < MR; ++m)
#pragma unroll
      for (int n = 0; n < 4; ++n)
        acc[m][n] = __builtin_amdgcn_mfma_f32_16x16x32_bf16(af[m], bfr[n], acc[m][n], 0, 0, 0);
  };

#define GB_BARRIER() do { \
    asm volatile("s_waitcnt lgkmcnt(0)" ::: "memory"); \
    __builtin_amdgcn_sched_barrier(0); \
    __builtin_amdgcn_s_barrier(); \
  } while (0)

  RS ra_, rb_;
  loadT(ra_, 0);
  loadT(rb_, 1);
  storeT(ra_, 0);
  GB_BARRIER();

  for (int kt = 0; kt < NK; kt += 2) {
    if (kt + 2 < NK) loadT(ra_, kt + 2);
    comp(0);
    storeT(rb_, 1);
    GB_BARRIER();
    if (kt + 3 < NK) loadT(rb_, kt + 3);
    comp(1);
    if (kt + 2 < NK) {
      storeT(ra_, 0);
      GB_BARRIER();
    }
  }
#undef GB_BARRIER

#pragma unroll
  for (int n = 0; n < 4; ++n) {
    const int col = n0 + n * 16 + r16;
    const float bv = (bias && nsplit == 1) ? bias[col] : 0.f;
#pragma unroll
    for (int m = 0; m < MR; ++m) {
      const int rbase = m0 + wv * WM + m * 16 + (lane >> 4) * 4;
#pragma unroll
      for (int r = 0; r < 4; ++r) {
        float v = acc[m][n][r] + bv;
        if (act) v = fmaxf(v, 0.f);
        if (nsplit > 1) {
          atomicAdd(&C[(size_t)(rbase + r) * ldc + col_off + col], v);
        } else {
          C[(size_t)(rbase + r) * ldc + col_off + col] = v;
        }
      }
    }
  }
}

// ---- prep: X0=[emb|h], X1=[emb|0]; bias-init alog/xact/gi/gh ---------------
__global__ void prep_kernel(const int* __restrict__ ids, const float* __restrict__ hid,
                            const float* __restrict__ emb,
                            const float* __restrict__ attn_b, const float* __restrict__ comb_b,
                            const float* __restrict__ b_ih, const float* __restrict__ b_hh,
                            float* __restrict__ X0, float* __restrict__ X1,
                            float* __restrict__ alog, float* __restrict__ xact,
                            float* __restrict__ gi, float* __restrict__ gh)
{
  const int b = blockIdx.x, t = threadIdx.x;
  const int row = ids[b];
  f32x4 e = *reinterpret_cast<const f32x4*>(emb + (size_t)row * Hdim + t * 4);
  *reinterpret_cast<f32x4*>(X0 + (size_t)b * 2048 + t * 4) = e;
  *reinterpret_cast<f32x4*>(X1 + (size_t)b * 2048 + t * 4) = e;
  f32x4 h = *reinterpret_cast<const f32x4*>(hid + (size_t)b * Hdim + t * 4);
  *reinterpret_cast<f32x4*>(X0 + (size_t)b * 2048 + 1024 + t * 4) = h;
  f32x4 z4 = {0.f, 0.f, 0.f, 0.f};
  *reinterpret_cast<f32x4*>(X1 + (size_t)b * 2048 + 1024 + t * 4) = z4;
  if (t < 128)
    *reinterpret_cast<f32x4*>(alog + (size_t)b * Ldim + t * 4) =
        *reinterpret_cast<const f32x4*>(attn_b + t * 4);
  *reinterpret_cast<f32x4*>(xact + (size_t)b * Hdim + t * 4) =
      *reinterpret_cast<const f32x4*>(comb_b + t * 4);
#pragma unroll
  for (int i = 0; i < 3; ++i) {
    *reinterpret_cast<f32x4*>(gi + (size_t)b * 3072 + i * 1024 + t * 4) =
        *reinterpret_cast<const f32x4*>(b_ih + i * 1024 + t * 4);
    *reinterpret_cast<f32x4*>(gh + (size_t)b * 3072 + i * 1024 + t * 4) =
        *reinterpret_cast<const f32x4*>(b_hh + i * 1024 + t * 4);
  }
}

// ---- encoder transpose: encT[h][l] = enc[l][h] -----------------------------
__global__ void transpose_kernel(const float* __restrict__ enc, float* __restrict__ encT)
{
  __shared__ float tile[64][65];
  const int l0 = blockIdx.x * 64, h0 = blockIdx.y * 64;
  const int t = threadIdx.x;
  const int c = t & 63, rr = t >> 6;
#pragma unroll
  for (int p = 0; p < 16; ++p) {
    const int r = p * 4 + rr;
    tile[r][c] = enc[(size_t)(l0 + r) * Hdim + h0 + c];
  }
  __syncthreads();
#pragma unroll
  for (int p = 0; p < 16; ++p) {
    const int r = p * 4 + rr;
    encT[(size_t)(h0 + r) * Ldim + l0 + c] = tile[c][r];
  }
}

// ---- softmax over L=512 per row --------------------------------------------
__global__ void attn_softmax_kernel(const float* __restrict__ logits, float* __restrict__ wout)
{
  __shared__ float red[256];
  const int b = blockIdx.x, t = threadIdx.x;
  const float x0 = logits[b * Ldim + t];
  const float x1 = logits[b * Ldim + 256 + t];
  red[t] = fmaxf(x0, x1); __syncthreads();
  for (int o = 128; o > 0; o >>= 1) { if (t < o) red[t] = fmaxf(red[t], red[t + o]); __syncthreads(); }
  const float m = red[0]; __syncthreads();
  const float e0 = __expf(x0 - m), e1 = __expf(x1 - m);
  red[t] = e0 + e1; __syncthreads();
  for (int o = 128; o > 0; o >>= 1) { if (t < o) red[t] += red[t + o]; __syncthreads(); }
  const float inv = 1.f / red[0];
  wout[b * Ldim + t]       = e0 * inv;
  wout[b * Ldim + 256 + t] = e1 * inv;
}

// ---- GRU pointwise ---------------------------------------------------------
DEVI float sigm(float x) { return 1.f / (1.f + __expf(-x)); }

__global__ void gru_kernel(const float* __restrict__ gi, const float* __restrict__ gh,
                           const float* __restrict__ hin,
                           float* __restrict__ hnew, unsigned short* __restrict__ hnbf)
{
  const int idx = blockIdx.x * 256 + threadIdx.x;
  const int b = idx >> 10, j = idx & 1023;
  const float* gib = gi + (size_t)b * 3072;
  const float* ghb = gh + (size_t)b * 3072;
  const float r = sigm(gib[j] + ghb[j]);
  const float z = sigm(gib[1024 + j] + ghb[1024 + j]);
  const float n = tanhf(gib[2048 + j] + r * ghb[2048 + j]);
  const float h = hin[idx];
  const float hn = (1.f - z) * n + z * h;
  hnew[idx] = hn;
  hnbf[idx] = f2bf(hn);
}

// ---- LSE: reduce per-block partials to lse[b] ------------------------------
__global__ void lse_reduce(const float2* __restrict__ part, int npart,
                           float* __restrict__ lse)
{
  __shared__ float rm[256], rs[256];
  const int b = blockIdx.x, t = threadIdx.x;
  float m = -1e30f, s = 0.f;
  for (int j = t; j < npart; j += 256) {
    const float2 p = part[(size_t)b * npart + j];
    const float nm = fmaxf(m, p.x);
    s = s * __expf(m - nm) + p.y * __expf(p.x - nm);
    m = nm;
  }
  rm[t] = m; rs[t] = s; __syncthreads();
  for (int o = 128; o > 0; o >>= 1) {
    if (t < o) {
      const float m2 = rm[t + o], s2 = rs[t + o];
      const float nm = fmaxf(rm[t], m2);
      rs[t] = rs[t] * __expf(rm[t] - nm) + s2 * __expf(m2 - nm);
      rm[t] = nm;
    }
    __syncthreads();
  }
  if (t == 0) lse[b] = rm[0] + __logf(rs[0]);
}

// ---- subtract lse in place (2048 blocks, full-BW streaming) ----------------
__global__ void lsm_sub(const float* __restrict__ lse, float* __restrict__ out)
{
  const int b = blockIdx.x >> 3, c = blockIdx.x & 7;
  const float l = lse[b];
  f32x4* row4 = reinterpret_cast<f32x4*>(out + (size_t)b * Vdim) + c * 1000;
  for (int i = threadIdx.x; i < 1000; i += 256) {
    f32x4 x = row4[i];
    x[0] -= l; x[1] -= l; x[2] -= l; x[3] -= l;
    row4[i] = x;
  }
}

// ---------------------------------------------------------------------------
extern "C" void kernel_launch(void* const* d_in, const int* in_sizes, int n_in,
                              void* d_out, int out_size, void* d_ws, size_t ws_size,
                              hipStream_t stream)
{
  (void)in_sizes; (void)n_in; (void)out_size; (void)ws_size;

  const int*   ids    = (const int*)  d_in[0];
  const float* hid    = (const float*)d_in[1];
  const float* enc    = (const float*)d_in[2];
  const float* emb    = (const float*)d_in[3];
  const float* attn_W = (const float*)d_in[4];
  const float* attn_b = (const float*)d_in[5];
  const float* comb_W = (const float*)d_in[6];
  const float* comb_b = (const float*)d_in[7];
  const float* W_ih   = (const float*)d_in[8];
  const float* W_hh   = (const float*)d_in[9];
  const float* b_ih   = (const float*)d_in[10];
  const float* b_hh   = (const float*)d_in[11];
  const float* out_W  = (const float*)d_in[12];
  const float* out_b  = (const float*)d_in[13];

  float* out_logits = (float*)d_out;                       // [B,V]
  float* out_h      = out_logits + (size_t)Bdim * Vdim;    // [B,H]
  float* out_attw   = out_h + (size_t)Bdim * Hdim;         // [B,L]

  char* w = (char*)d_ws;
  float* X0   = (float*)w; w += (size_t)Bdim * 2048 * 4;
  float* X1   = (float*)w; w += (size_t)Bdim * 2048 * 4;
  float* encT = (float*)w; w += (size_t)Hdim * Ldim * 4;
  float* alog = (float*)w; w += (size_t)Bdim * Ldim * 4;
  float* xact = (float*)w; w += (size_t)Bdim * Hdim * 4;
  float* gi   = (float*)w; w += (size_t)Bdim * 3 * Hdim * 4;
  float* gh   = (float*)w; w += (size_t)Bdim * 3 * Hdim * 4;
  unsigned short* hnbf = (unsigned short*)w; w += (size_t)Bdim * Hdim * 2;
  float2* plse = (float2*)w; w += (size_t)Bdim * (Vdim / 32) * 8;
  float* lse  = (float*)w; w += (size_t)Bdim * 4;

  prep_kernel<<<Bdim, 256, 0, stream>>>(ids, hid, emb, attn_b, comb_b, b_ih, b_hh,
                                        X0, X1, alog, xact, gi, gh);
  transpose_kernel<<<dim3(Ldim / 64, Hdim / 64), 256, 0, stream>>>(enc, encT);

  // attn logits [B,L] += X0 @ attn_W^T   (split-K=16 -> 256 blocks)
  gemm_bt<32, false, false><<<dim3(Ldim / 64, 2, 16), 256, 0, stream>>>(
      X0, attn_W, nullptr, nullptr, nullptr, alog, nullptr,
      2048, Ldim, 0, 0, 0, 16);
  attn_softmax_kernel<<<Bdim, 256, 0, stream>>>(alog, out_attw);

  // attn_applied [B,H] += attn_w @ encT^T -> X1 right half (split-K=8 -> 256)
  gemm_bt<32, false, false><<<dim3(Hdim / 64, 2, 8), 256, 0, stream>>>(
      out_attw, encT, nullptr, nullptr, nullptr, X1, nullptr,
      512, 2048, 1024, 0, 0, 8);

  // xact [B,H] += X1 @ comb_W^T  (split-K=16 -> 512 blocks)
  gemm_bt<32, false, false><<<dim3(Hdim / 64, 2, 16), 256, 0, stream>>>(
      X1, comb_W, nullptr, nullptr, nullptr, xact, nullptr,
      2048, Hdim, 0, 0, 0, 16);

  // gi += relu(xact) @ W_ih^T ; gh += h @ W_hh^T  (dual, split-K=8 -> 1536)
  gemm_bt<32, false, true><<<dim3(3 * Hdim / 64, 2, 16), 256, 0, stream>>>(
      xact, W_ih, hid, W_hh, nullptr, gi, gh,
      1024, 3 * Hdim, 0, 0, 1, 8);

  gru_kernel<<<Bdim * Hdim / 256, 256, 0, stream>>>(gi, gh, hid, out_h, hnbf);

  // logits [B,V] = h_new @ out_W^T + out_b  (high-occupancy flat GEMM)
  gemm_flat3<<<Vdim / 32, 256, 0, stream>>>(hnbf, out_W, out_b, out_logits, plse);

  lse_reduce<<<Bdim, 256, 0, stream>>>(plse, Vdim / 32, lse);
  lsm_sub<<<Bdim * 8, 256, 0, stream>>>(lse, out_logits);
}

// Round 6
// 137.344 us; speedup vs baseline: 1.4526x; 1.4526x over previous
//
#include <hip/hip_runtime.h>
#include <hip/hip_bf16.h>
#include <cstdint>

#define DEVI __device__ __forceinline__

typedef __bf16 bf16x8 __attribute__((ext_vector_type(8)));
typedef float  f32x4  __attribute__((ext_vector_type(4)));

constexpr int Hdim = 1024;
constexpr int Vdim = 32000;
constexpr int Ldim = 512;
constexpr int Bdim = 256;

DEVI unsigned short f2bf(float f) {
  __bf16 h = (__bf16)f;                       // RNE
  return __builtin_bit_cast(unsigned short, h);
}

// ===========================================================================
// gemm_flat4: C[256 x 32000] = A[256x1024](bf16) @ W[32000x1024](f32)^T + bias
// BYTES-MINIMIZING version. R1-R5 invariant: dur = total_read_bytes / ~5 TB/s
// regardless of schedule/occupancy. So: N-tile 128 (grid 250) cuts the A
// re-read from 512 MB (Ntile 32) to 128 MB; W read exactly once (131 MB).
//   - 1024 threads = 16 waves; wave = 16 M-rows x 128 N-cols (acc 32 VGPR).
//   - per K-step: stage W tile 128rows x 32k fp32 -> bf16 -> LDS (each thread
//     1 f32x4 load + 1 ushort4 ds_write), double-buffered (2 x 9 KB, pitch 36
//     -> <=2-way bank aliasing on ds_read = free).
//   - A frag: 1 uint4 direct-to-reg per wave per step (ping-pong reg sets).
//   - flat3's proven ping-pong loop structure, 2 barriers / 2 K-steps.
// MFMA 16x16x32_bf16; C/D: col=lane&15, row=(lane>>4)*4+reg (m89-verified).
// ===========================================================================
constexpr int FP4 = 36;              // LDS row pitch in bf16 elems

__global__ __launch_bounds__(1024, 4)
void gemm_flat4(const unsigned short* __restrict__ A,
                const float* __restrict__ W,
                const float* __restrict__ bias,
                float* __restrict__ C,
                float2* __restrict__ plse)
{
  __shared__ unsigned short lW[2][128 * FP4];   // 2 x 9216 B

  const int t    = threadIdx.x;
  const int lane = t & 63;
  const int wv   = t >> 6;            // 0..15 -> M rows [wv*16, wv*16+16)
  const int r16  = lane & 15;
  const int k8   = (lane >> 4) * 8;
  const int n0   = blockIdx.x * 128;

  const int srow = t >> 3;            // staging row 0..127
  const int stc  = (t & 7) * 4;       // staging k-elem 0..28

  f32x4 acc[8];
#pragma unroll
  for (int n = 0; n < 8; ++n)
#pragma unroll
    for (int r = 0; r < 4; ++r) acc[n][r] = 0.f;

  uint4 a0_, a1_;
  f32x4 w0_, w1_;

#define LOADW(RW, KT) \
    RW = *reinterpret_cast<const f32x4*>( \
        W + (size_t)(n0 + srow) * 1024 + (KT) * 32 + stc)

#define LOADA(RA, KT) \
    RA = *reinterpret_cast<const uint4*>( \
        A + (size_t)(wv * 16 + r16) * 1024 + (KT) * 32 + k8)

#define STOREW(RW, BUF) do {                                                   \
    ushort4 u_;                                                                \
    u_.x = f2bf(RW[0]); u_.y = f2bf(RW[1]);                                    \
    u_.z = f2bf(RW[2]); u_.w = f2bf(RW[3]);                                    \
    *reinterpret_cast<ushort4*>(&lW[BUF][srow * FP4 + stc]) = u_;              \
  } while (0)

#define COMP(RA, BUF) do {                                                     \
    _Pragma("unroll")                                                          \
    for (int n = 0; n < 8; ++n) {                                              \
      bf16x8 bw_ = *reinterpret_cast<const bf16x8*>(                           \
          &lW[BUF][(n * 16 + r16) * FP4 + k8]);                                \
      acc[n] = __builtin_amdgcn_mfma_f32_16x16x32_bf16(                        \
          __builtin_bit_cast(bf16x8, RA), bw_, acc[n], 0, 0, 0);               \
    }                                                                          \
  } while (0)

  LOADW(w0_, 0); LOADA(a0_, 0);
  STOREW(w0_, 0);
  __syncthreads();

  for (int kt = 0; kt < 32; kt += 2) {
    // step kt: compute buf0, stage kt+1 -> buf1
    LOADW(w1_, kt + 1); LOADA(a1_, kt + 1);
    COMP(a0_, 0);
    STOREW(w1_, 1);
    __syncthreads();
    // step kt+1: compute buf1, stage kt+2 -> buf0
    { const int kn_ = (kt + 2 < 32) ? kt + 2 : 31;
      LOADW(w0_, kn_); LOADA(a0_, kn_); }
    COMP(a1_, 1);
    STOREW(w0_, 0);
    __syncthreads();
  }

#undef COMP
#undef STOREW
#undef LOADA
#undef LOADW

  // ---------------- epilogue: bias, store, LSE partials --------------------
#pragma unroll
  for (int n = 0; n < 8; ++n) {
    const int col = n0 + n * 16 + r16;
    const float bv = bias[col];
    const int rbase = wv * 16 + (lane >> 4) * 4;
#pragma unroll
    for (int r = 0; r < 4; ++r) {
      const float v = acc[n][r] + bv;
      acc[n][r] = v;
      C[(size_t)(rbase + r) * Vdim + col] = v;
    }
  }
#pragma unroll
  for (int r = 0; r < 4; ++r) {
    float mx = -1e30f;
#pragma unroll
    for (int n = 0; n < 8; ++n) mx = fmaxf(mx, acc[n][r]);
#pragma unroll
    for (int o = 1; o < 16; o <<= 1) mx = fmaxf(mx, __shfl_xor(mx, o, 16));
    float s = 0.f;
#pragma unroll
    for (int n = 0; n < 8; ++n) s += __expf(acc[n][r] - mx);
#pragma unroll
    for (int o = 1; o < 16; o <<= 1) s += __shfl_xor(s, o, 16);
    if (r16 == 0) {
      const int row = wv * 16 + (lane >> 4) * 4 + r;
      plse[(size_t)row * gridDim.x + blockIdx.x] = make_float2(mx, s);
    }
  }
}

// ---------------------------------------------------------------------------
// Small-GEMM engine: reg-staged dbuf, split-K atomics (bias pre-initialized)
// ---------------------------------------------------------------------------
template<int WM, bool ABF16, bool DUAL>
__global__ __launch_bounds__(256, 2)
void gemm_bt(const void* __restrict__ Av0, const float* __restrict__ Wt0,
             const void* __restrict__ Av1, const float* __restrict__ Wt1,
             const float* __restrict__ bias,
             float* __restrict__ C0, float* __restrict__ C1,
             int K, int ldc, int col_off, int act, int aact0,
             int nsplit)
{
  constexpr int MT    = 4 * WM;
  constexpr int PITCH = 40;
  constexpr int ITA   = MT / 32;
  constexpr int MR    = WM / 16;

  __shared__ unsigned short lA[2 * MT * PITCH];
  __shared__ unsigned short lW[2 * 64 * PITCH];

  const int t  = threadIdx.x;
  const int m0 = blockIdx.y * MT;
  const int n0 = blockIdx.x * 64;

  int kz = blockIdx.z, half = 0;
  if (DUAL) { half = (kz >= nsplit) ? 1 : 0; kz -= half * nsplit; }
  const int NK = K / (32 * nsplit);
  const int kb = kz * NK;

  const void*  Av = (DUAL && half) ? Av1 : Av0;
  const float* Wt = (DUAL && half) ? Wt1 : Wt0;
  float*       C  = (DUAL && half) ? C1  : C0;
  const int  aact = (DUAL && half) ? 0 : aact0;

  const int tr = t >> 3;
  const int tc = (t & 7) * 4;

  const float*          Af = ABF16 ? nullptr : ((const float*)Av) + (size_t)m0 * K;
  const unsigned short* Ab = ABF16 ? ((const unsigned short*)Av) + (size_t)m0 * K : nullptr;
  const float*          Wb = Wt + (size_t)n0 * K;

  const int lane = t & 63;
  const int wv   = t >> 6;
  const int r16  = lane & 15;
  const int k8   = (lane >> 4) * 8;

  f32x4 acc[MR][4];
#pragma unroll
  for (int m = 0; m < MR; ++m)
#pragma unroll
    for (int n = 0; n < 4; ++n)
#pragma unroll
      for (int r = 0; r < 4; ++r) acc[m][n][r] = 0.f;

  struct RS { f32x4 ra[ITA]; ushort4 rab[ITA]; f32x4 rw[2]; };

  auto loadT = [&](RS& rg, int kt) {
    const int ko = (kb + kt) * 32 + tc;
    if constexpr (ABF16) {
      const unsigned short* ap = Ab + ko;
#pragma unroll
      for (int i = 0; i < ITA; ++i)
        rg.rab[i] = *reinterpret_cast<const ushort4*>(ap + (size_t)(tr + 32 * i) * K);
    } else {
      const float* ap = Af + ko;
#pragma unroll
      for (int i = 0; i < ITA; ++i)
        rg.ra[i] = *reinterpret_cast<const f32x4*>(ap + (size_t)(tr + 32 * i) * K);
    }
    const float* wp = Wb + ko;
#pragma unroll
    for (int i = 0; i < 2; ++i)
      rg.rw[i] = *reinterpret_cast<const f32x4*>(wp + (size_t)(tr + 32 * i) * K);
  };

  auto storeT = [&](RS& rg, int bo) {
    unsigned short* sA = &lA[bo * MT * PITCH];
    unsigned short* sW = &lW[bo * 64 * PITCH];
#pragma unroll
    for (int i = 0; i < ITA; ++i) {
      ushort4 u;
      if constexpr (ABF16) u = rg.rab[i];
      else {
        f32x4 v = rg.ra[i];
        if (aact) { v[0]=fmaxf(v[0],0.f); v[1]=fmaxf(v[1],0.f);
                    v[2]=fmaxf(v[2],0.f); v[3]=fmaxf(v[3],0.f); }
        u.x = f2bf(v[0]); u.y = f2bf(v[1]); u.z = f2bf(v[2]); u.w = f2bf(v[3]);
      }
      *reinterpret_cast<ushort4*>(&sA[(tr + 32 * i) * PITCH + tc]) = u;
    }
#pragma unroll
    for (int i = 0; i < 2; ++i) {
      f32x4 v = rg.rw[i]; ushort4 u;
      u.x = f2bf(v[0]); u.y = f2bf(v[1]); u.z = f2bf(v[2]); u.w = f2bf(v[3]);
      *reinterpret_cast<ushort4*>(&sW[(tr + 32 * i) * PITCH + tc]) = u;
    }
  };

  auto comp = [&](int bo) {
    const unsigned short* sA = &lA[bo * MT * PITCH];
    const unsigned short* sW = &lW[bo * 64 * PITCH];
    bf16x8 af[MR], bfr[4];
#pragma unroll
    for (int m = 0; m < MR; ++m)
      af[m] = *reinterpret_cast<const bf16x8*>(&sA[(wv * WM + m * 16 + r16) * PITCH + k8]);
#pragma unroll
    for (int n = 0; n < 4; ++n)
      bfr[n] = *reinterpret_cast<const bf16x8*>(&sW[(n * 16 + r16) * PITCH + k8]);
#pragma unroll
    for (int m = 0; m < MR; ++m)
#pragma unroll
      for (int n = 0; n < 4; ++n)
        acc[m][n] = __builtin_amdgcn_mfma_f32_16x16x32_bf16(af[m], bfr[n], acc[m][n], 0, 0, 0);
  };

#define GB_BARRIER() do { \
    asm volatile("s_waitcnt lgkmcnt(0)" ::: "memory"); \
    __builtin_amdgcn_sched_barrier(0); \
    __builtin_amdgcn_s_barrier(); \
  } while (0)

  RS ra_, rb_;
  loadT(ra_, 0);
  loadT(rb_, 1);
  storeT(ra_, 0);
  GB_BARRIER();

  for (int kt = 0; kt < NK; kt += 2) {
    if (kt + 2 < NK) loadT(ra_, kt + 2);
    comp(0);
    storeT(rb_, 1);
    GB_BARRIER();
    if (kt + 3 < NK) loadT(rb_, kt + 3);
    comp(1);
    if (kt + 2 < NK) {
      storeT(ra_, 0);
      GB_BARRIER();
    }
  }
#undef GB_BARRIER

#pragma unroll
  for (int n = 0; n < 4; ++n) {
    const int col = n0 + n * 16 + r16;
    const float bv = (bias && nsplit == 1) ? bias[col] : 0.f;
#pragma unroll
    for (int m = 0; m < MR; ++m) {
      const int rbase = m0 + wv * WM + m * 16 + (lane >> 4) * 4;
#pragma unroll
      for (int r = 0; r < 4; ++r) {
        float v = acc[m][n][r] + bv;
        if (act) v = fmaxf(v, 0.f);
        if (nsplit > 1) {
          atomicAdd(&C[(size_t)(rbase + r) * ldc + col_off + col], v);
        } else {
          C[(size_t)(rbase + r) * ldc + col_off + col] = v;
        }
      }
    }
  }
}

// ---- prep: X0=[emb|h], X1=[emb|0]; bias-init alog/xact/gi/gh ---------------
__global__ void prep_kernel(const int* __restrict__ ids, const float* __restrict__ hid,
                            const float* __restrict__ emb,
                            const float* __restrict__ attn_b, const float* __restrict__ comb_b,
                            const float* __restrict__ b_ih, const float* __restrict__ b_hh,
                            float* __restrict__ X0, float* __restrict__ X1,
                            float* __restrict__ alog, float* __restrict__ xact,
                            float* __restrict__ gi, float* __restrict__ gh)
{
  const int b = blockIdx.x, t = threadIdx.x;
  const int row = ids[b];
  f32x4 e = *reinterpret_cast<const f32x4*>(emb + (size_t)row * Hdim + t * 4);
  *reinterpret_cast<f32x4*>(X0 + (size_t)b * 2048 + t * 4) = e;
  *reinterpret_cast<f32x4*>(X1 + (size_t)b * 2048 + t * 4) = e;
  f32x4 h = *reinterpret_cast<const f32x4*>(hid + (size_t)b * Hdim + t * 4);
  *reinterpret_cast<f32x4*>(X0 + (size_t)b * 2048 + 1024 + t * 4) = h;
  f32x4 z4 = {0.f, 0.f, 0.f, 0.f};
  *reinterpret_cast<f32x4*>(X1 + (size_t)b * 2048 + 1024 + t * 4) = z4;
  if (t < 128)
    *reinterpret_cast<f32x4*>(alog + (size_t)b * Ldim + t * 4) =
        *reinterpret_cast<const f32x4*>(attn_b + t * 4);
  *reinterpret_cast<f32x4*>(xact + (size_t)b * Hdim + t * 4) =
      *reinterpret_cast<const f32x4*>(comb_b + t * 4);
#pragma unroll
  for (int i = 0; i < 3; ++i) {
    *reinterpret_cast<f32x4*>(gi + (size_t)b * 3072 + i * 1024 + t * 4) =
        *reinterpret_cast<const f32x4*>(b_ih + i * 1024 + t * 4);
    *reinterpret_cast<f32x4*>(gh + (size_t)b * 3072 + i * 1024 + t * 4) =
        *reinterpret_cast<const f32x4*>(b_hh + i * 1024 + t * 4);
  }
}

// ---- encoder transpose: encT[h][l] = enc[l][h] -----------------------------
__global__ void transpose_kernel(const float* __restrict__ enc, float* __restrict__ encT)
{
  __shared__ float tile[64][65];
  const int l0 = blockIdx.x * 64, h0 = blockIdx.y * 64;
  const int t = threadIdx.x;
  const int c = t & 63, rr = t >> 6;
#pragma unroll
  for (int p = 0; p < 16; ++p) {
    const int r = p * 4 + rr;
    tile[r][c] = enc[(size_t)(l0 + r) * Hdim + h0 + c];
  }
  __syncthreads();
#pragma unroll
  for (int p = 0; p < 16; ++p) {
    const int r = p * 4 + rr;
    encT[(size_t)(h0 + r) * Ldim + l0 + c] = tile[c][r];
  }
}

// ---- softmax over L=512 per row --------------------------------------------
__global__ void attn_softmax_kernel(const float* __restrict__ logits, float* __restrict__ wout)
{
  __shared__ float red[256];
  const int b = blockIdx.x, t = threadIdx.x;
  const float x0 = logits[b * Ldim + t];
  const float x1 = logits[b * Ldim + 256 + t];
  red[t] = fmaxf(x0, x1); __syncthreads();
  for (int o = 128; o > 0; o >>= 1) { if (t < o) red[t] = fmaxf(red[t], red[t + o]); __syncthreads(); }
  const float m = red[0]; __syncthreads();
  const float e0 = __expf(x0 - m), e1 = __expf(x1 - m);
  red[t] = e0 + e1; __syncthreads();
  for (int o = 128; o > 0; o >>= 1) { if (t < o) red[t] += red[t + o]; __syncthreads(); }
  const float inv = 1.f / red[0];
  wout[b * Ldim + t]       = e0 * inv;
  wout[b * Ldim + 256 + t] = e1 * inv;
}

// ---- GRU pointwise ---------------------------------------------------------
DEVI float sigm(float x) { return 1.f / (1.f + __expf(-x)); }

__global__ void gru_kernel(const float* __restrict__ gi, const float* __restrict__ gh,
                           const float* __restrict__ hin,
                           float* __restrict__ hnew, unsigned short* __restrict__ hnbf)
{
  const int idx = blockIdx.x * 256 + threadIdx.x;
  const int b = idx >> 10, j = idx & 1023;
  const float* gib = gi + (size_t)b * 3072;
  const float* ghb = gh + (size_t)b * 3072;
  const float r = sigm(gib[j] + ghb[j]);
  const float z = sigm(gib[1024 + j] + ghb[1024 + j]);
  const float n = tanhf(gib[2048 + j] + r * ghb[2048 + j]);
  const float h = hin[idx];
  const float hn = (1.f - z) * n + z * h;
  hnew[idx] = hn;
  hnbf[idx] = f2bf(hn);
}

// ---- LSE: reduce per-block partials to lse[b] ------------------------------
__global__ void lse_reduce(const float2* __restrict__ part, int npart,
                           float* __restrict__ lse)
{
  __shared__ float rm[256], rs[256];
  const int b = blockIdx.x, t = threadIdx.x;
  float m = -1e30f, s = 0.f;
  for (int j = t; j < npart; j += 256) {
    const float2 p = part[(size_t)b * npart + j];
    const float nm = fmaxf(m, p.x);
    s = s * __expf(m - nm) + p.y * __expf(p.x - nm);
    m = nm;
  }
  rm[t] = m; rs[t] = s; __syncthreads();
  for (int o = 128; o > 0; o >>= 1) {
    if (t < o) {
      const float m2 = rm[t + o], s2 = rs[t + o];
      const float nm = fmaxf(rm[t], m2);
      rs[t] = rs[t] * __expf(rm[t] - nm) + s2 * __expf(m2 - nm);
      rm[t] = nm;
    }
    __syncthreads();
  }
  if (t == 0) lse[b] = rm[0] + __logf(rs[0]);
}

// ---- subtract lse in place (2048 blocks, full-BW streaming) ----------------
__global__ void lsm_sub(const float* __restrict__ lse, float* __restrict__ out)
{
  const int b = blockIdx.x >> 3, c = blockIdx.x & 7;
  const float l = lse[b];
  f32x4* row4 = reinterpret_cast<f32x4*>(out + (size_t)b * Vdim) + c * 1000;
  for (int i = threadIdx.x; i < 1000; i += 256) {
    f32x4 x = row4[i];
    x[0] -= l; x[1] -= l; x[2] -= l; x[3] -= l;
    row4[i] = x;
  }
}

// ---------------------------------------------------------------------------
extern "C" void kernel_launch(void* const* d_in, const int* in_sizes, int n_in,
                              void* d_out, int out_size, void* d_ws, size_t ws_size,
                              hipStream_t stream)
{
  (void)in_sizes; (void)n_in; (void)out_size; (void)ws_size;

  const int*   ids    = (const int*)  d_in[0];
  const float* hid    = (const float*)d_in[1];
  const float* enc    = (const float*)d_in[2];
  const float* emb    = (const float*)d_in[3];
  const float* attn_W = (const float*)d_in[4];
  const float* attn_b = (const float*)d_in[5];
  const float* comb_W = (const float*)d_in[6];
  const float* comb_b = (const float*)d_in[7];
  const float* W_ih   = (const float*)d_in[8];
  const float* W_hh   = (const float*)d_in[9];
  const float* b_ih   = (const float*)d_in[10];
  const float* b_hh   = (const float*)d_in[11];
  const float* out_W  = (const float*)d_in[12];
  const float* out_b  = (const float*)d_in[13];

  float* out_logits = (float*)d_out;                       // [B,V]
  float* out_h      = out_logits + (size_t)Bdim * Vdim;    // [B,H]
  float* out_attw   = out_h + (size_t)Bdim * Hdim;         // [B,L]

  char* w = (char*)d_ws;
  float* X0   = (float*)w; w += (size_t)Bdim * 2048 * 4;
  float* X1   = (float*)w; w += (size_t)Bdim * 2048 * 4;
  float* encT = (float*)w; w += (size_t)Hdim * Ldim * 4;
  float* alog = (float*)w; w += (size_t)Bdim * Ldim * 4;
  float* xact = (float*)w; w += (size_t)Bdim * Hdim * 4;
  float* gi   = (float*)w; w += (size_t)Bdim * 3 * Hdim * 4;
  float* gh   = (float*)w; w += (size_t)Bdim * 3 * Hdim * 4;
  unsigned short* hnbf = (unsigned short*)w; w += (size_t)Bdim * Hdim * 2;
  float2* plse = (float2*)w; w += (size_t)Bdim * (Vdim / 32) * 8;
  float* lse  = (float*)w; w += (size_t)Bdim * 4;

  prep_kernel<<<Bdim, 256, 0, stream>>>(ids, hid, emb, attn_b, comb_b, b_ih, b_hh,
                                        X0, X1, alog, xact, gi, gh);
  transpose_kernel<<<dim3(Ldim / 64, Hdim / 64), 256, 0, stream>>>(enc, encT);

  // attn logits [B,L] += X0 @ attn_W^T   (split-K=8, bias pre-init)
  gemm_bt<32, false, false><<<dim3(Ldim / 64, 2, 8), 256, 0, stream>>>(
      X0, attn_W, nullptr, nullptr, nullptr, alog, nullptr,
      2048, Ldim, 0, 0, 0, 8);
  attn_softmax_kernel<<<Bdim, 256, 0, stream>>>(alog, out_attw);

  // attn_applied [B,H] += attn_w @ encT^T -> X1 right half (split-K=4)
  gemm_bt<32, false, false><<<dim3(Hdim / 64, 2, 4), 256, 0, stream>>>(
      out_attw, encT, nullptr, nullptr, nullptr, X1, nullptr,
      512, 2048, 1024, 0, 0, 4);

  // xact [B,H] += X1 @ comb_W^T  (split-K=8; ReLU deferred to gi's A-staging)
  gemm_bt<32, false, false><<<dim3(Hdim / 64, 2, 8), 256, 0, stream>>>(
      X1, comb_W, nullptr, nullptr, nullptr, xact, nullptr,
      2048, Hdim, 0, 0, 0, 8);

  // gi += relu(xact) @ W_ih^T ; gh += h @ W_hh^T  (dual, split-K=4)
  gemm_bt<32, false, true><<<dim3(3 * Hdim / 64, 2, 8), 256, 0, stream>>>(
      xact, W_ih, hid, W_hh, nullptr, gi, gh,
      1024, 3 * Hdim, 0, 0, 1, 4);

  gru_kernel<<<Bdim * Hdim / 256, 256, 0, stream>>>(gi, gh, hid, out_h, hnbf);

  // logits [B,V] = h_new @ out_W^T + out_b  (bytes-minimal GEMM, Ntile 128)
  gemm_flat4<<<Vdim / 128, 1024, 0, stream>>>(hnbf, out_W, out_b, out_logits, plse);

  lse_reduce<<<Bdim, 256, 0, stream>>>(plse, Vdim / 128, lse);
  lsm_sub<<<Bdim * 8, 256, 0, stream>>>(lse, out_logits);
}

// Round 7
// 121.984 us; speedup vs baseline: 1.6355x; 1.1259x over previous
//
#include <hip/hip_runtime.h>
#include <hip/hip_bf16.h>
#include <cstdint>

#define DEVI __device__ __forceinline__

typedef __bf16 bf16x8 __attribute__((ext_vector_type(8)));
typedef float  f32x4  __attribute__((ext_vector_type(4)));

constexpr int Hdim = 1024;
constexpr int Vdim = 32000;
constexpr int Ldim = 512;
constexpr int Bdim = 256;

DEVI unsigned short f2bf(float f) {
  __bf16 h = (__bf16)f;                       // RNE
  return __builtin_bit_cast(unsigned short, h);
}

// ===========================================================================
// gemm_flat5: C[256 x 32000] = A[256x1024](bf16) @ W[32000x1024](f32)^T + bias
// flat4 (bytes-minimal: Ntile 128, grid 250, A re-read 128 MB, W once) +
// DEPTH-2 PIPELINE (r6 post-mortem: depth-1 exposes ~700cy/step of memory
// latency at 1 block/CU; measured 5500 cy/step vs 3200 VMEM floor):
//   - 4 LDS buffers (4 x 9 KB), period-4 static rotation.
//   - W regs: 2 sets; STOREW at step i stores the W loaded at step i-2
//     (wait-gap ~2 steps >> HBM latency). A regs: 4 sets, gap 4.
//   - one __syncthreads per step; buffer reuse (RAW and WAR) always 2
//     barriers apart. Tail: clamped redundant loads keep waits uniform.
// MFMA 16x16x32_bf16; C/D: col=lane&15, row=(lane>>4)*4+reg (m89-verified).
// ===========================================================================
constexpr int FP4 = 36;              // LDS row pitch in bf16 elems

__global__ __launch_bounds__(1024, 4)
void gemm_flat5(const unsigned short* __restrict__ A,
                const float* __restrict__ W,
                const float* __restrict__ bias,
                float* __restrict__ C,
                float2* __restrict__ plse)
{
  __shared__ unsigned short lW[4][128 * FP4];   // 4 x 9216 B = 36 KB

  const int t    = threadIdx.x;
  const int lane = t & 63;
  const int wv   = t >> 6;            // 0..15 -> M rows [wv*16, wv*16+16)
  const int r16  = lane & 15;
  const int k8   = (lane >> 4) * 8;
  const int n0   = blockIdx.x * 128;

  const int srow = t >> 3;            // staging row 0..127
  const int stc  = (t & 7) * 4;       // staging k-elem

  const float*          Wb = W + (size_t)(n0 + srow) * 1024 + stc;
  const unsigned short* Ab = A + (size_t)(wv * 16 + r16) * 1024 + k8;

  f32x4 acc[8];
#pragma unroll
  for (int n = 0; n < 8; ++n)
#pragma unroll
    for (int r = 0; r < 4; ++r) acc[n][r] = 0.f;

  f32x4 w0_, w1_;
  uint4 a0_, a1_, a2_, a3_;

#define LOADW(RW, KT) RW = *reinterpret_cast<const f32x4*>(Wb + (KT) * 32)
#define LOADA(RA, KT) RA = *reinterpret_cast<const uint4*>(Ab + (KT) * 32)

#define STOREW(RW, BUF) do {                                                   \
    ushort4 u_;                                                                \
    u_.x = f2bf(RW[0]); u_.y = f2bf(RW[1]);                                    \
    u_.z = f2bf(RW[2]); u_.w = f2bf(RW[3]);                                    \
    *reinterpret_cast<ushort4*>(&lW[BUF][srow * FP4 + stc]) = u_;              \
  } while (0)

#define COMP(RA, BUF) do {                                                     \
    _Pragma("unroll")                                                          \
    for (int n = 0; n < 8; ++n) {                                              \
      bf16x8 bw_ = *reinterpret_cast<const bf16x8*>(                           \
          &lW[BUF][(n * 16 + r16) * FP4 + k8]);                                \
      acc[n] = __builtin_amdgcn_mfma_f32_16x16x32_bf16(                        \
          __builtin_bit_cast(bf16x8, RA), bw_, acc[n], 0, 0, 0);               \
    }                                                                          \
  } while (0)

  // prologue: buf0<-t0, buf1<-t1, w regs hold t2,t3; a regs hold t0..t3
  LOADW(w0_, 0); LOADW(w1_, 1);
  LOADA(a0_, 0); LOADA(a1_, 1); LOADA(a2_, 2); LOADA(a3_, 3);
  STOREW(w0_, 0); LOADW(w0_, 2);
  STOREW(w1_, 1); LOADW(w1_, 3);
  __syncthreads();

  // steady state invariant entering step i: buf[i%4] = tile i, a[i%4] = A(i),
  // w[i%2] = W(i+2). STOREW's vmcnt wait targets a load issued 2 steps ago.
  for (int kt = 0; kt < 32; kt += 4) {
    COMP(a0_, 0);
    STOREW(w0_, 2);
    { const int kn = (kt + 4 < 32) ? kt + 4 : 31; LOADW(w0_, kn); LOADA(a0_, kn); }
    __syncthreads();

    COMP(a1_, 1);
    STOREW(w1_, 3);
    { const int kn = (kt + 5 < 32) ? kt + 5 : 31; LOADW(w1_, kn); LOADA(a1_, kn); }
    __syncthreads();

    COMP(a2_, 2);
    STOREW(w0_, 0);
    { const int kn = (kt + 6 < 32) ? kt + 6 : 31; LOADW(w0_, kn); LOADA(a2_, kn); }
    __syncthreads();

    COMP(a3_, 3);
    STOREW(w1_, 1);
    { const int kn = (kt + 7 < 32) ? kt + 7 : 31; LOADW(w1_, kn); LOADA(a3_, kn); }
    __syncthreads();
  }

#undef COMP
#undef STOREW
#undef LOADA
#undef LOADW

  // ---------------- epilogue: bias, store, LSE partials --------------------
#pragma unroll
  for (int n = 0; n < 8; ++n) {
    const int col = n0 + n * 16 + r16;
    const float bv = bias[col];
    const int rbase = wv * 16 + (lane >> 4) * 4;
#pragma unroll
    for (int r = 0; r < 4; ++r) {
      const float v = acc[n][r] + bv;
      acc[n][r] = v;
      C[(size_t)(rbase + r) * Vdim + col] = v;
    }
  }
#pragma unroll
  for (int r = 0; r < 4; ++r) {
    float mx = -1e30f;
#pragma unroll
    for (int n = 0; n < 8; ++n) mx = fmaxf(mx, acc[n][r]);
#pragma unroll
    for (int o = 1; o < 16; o <<= 1) mx = fmaxf(mx, __shfl_xor(mx, o, 16));
    float s = 0.f;
#pragma unroll
    for (int n = 0; n < 8; ++n) s += __expf(acc[n][r] - mx);
#pragma unroll
    for (int o = 1; o < 16; o <<= 1) s += __shfl_xor(s, o, 16);
    if (r16 == 0) {
      const int row = wv * 16 + (lane >> 4) * 4 + r;
      plse[(size_t)row * gridDim.x + blockIdx.x] = make_float2(mx, s);
    }
  }
}

// ---------------------------------------------------------------------------
// Small-GEMM engine: reg-staged dbuf, split-K atomics (bias pre-initialized)
// ---------------------------------------------------------------------------
template<int WM, bool ABF16, bool DUAL>
__global__ __launch_bounds__(256, 2)
void gemm_bt(const void* __restrict__ Av0, const float* __restrict__ Wt0,
             const void* __restrict__ Av1, const float* __restrict__ Wt1,
             const float* __restrict__ bias,
             float* __restrict__ C0, float* __restrict__ C1,
             int K, int ldc, int col_off, int act, int aact0,
             int nsplit)
{
  constexpr int MT    = 4 * WM;
  constexpr int PITCH = 40;
  constexpr int ITA   = MT / 32;
  constexpr int MR    = WM / 16;

  __shared__ unsigned short lA[2 * MT * PITCH];
  __shared__ unsigned short lW[2 * 64 * PITCH];

  const int t  = threadIdx.x;
  const int m0 = blockIdx.y * MT;
  const int n0 = blockIdx.x * 64;

  int kz = blockIdx.z, half = 0;
  if (DUAL) { half = (kz >= nsplit) ? 1 : 0; kz -= half * nsplit; }
  const int NK = K / (32 * nsplit);
  const int kb = kz * NK;

  const void*  Av = (DUAL && half) ? Av1 : Av0;
  const float* Wt = (DUAL && half) ? Wt1 : Wt0;
  float*       C  = (DUAL && half) ? C1  : C0;
  const int  aact = (DUAL && half) ? 0 : aact0;

  const int tr = t >> 3;
  const int tc = (t & 7) * 4;

  const float*          Af = ABF16 ? nullptr : ((const float*)Av) + (size_t)m0 * K;
  const unsigned short* Ab = ABF16 ? ((const unsigned short*)Av) + (size_t)m0 * K : nullptr;
  const float*          Wb = Wt + (size_t)n0 * K;

  const int lane = t & 63;
  const int wv   = t >> 6;
  const int r16  = lane & 15;
  const int k8   = (lane >> 4) * 8;

  f32x4 acc[MR][4];
#pragma unroll
  for (int m = 0; m < MR; ++m)
#pragma unroll
    for (int n = 0; n < 4; ++n)
#pragma unroll
      for (int r = 0; r < 4; ++r) acc[m][n][r] = 0.f;

  struct RS { f32x4 ra[ITA]; ushort4 rab[ITA]; f32x4 rw[2]; };

  auto loadT = [&](RS& rg, int kt) {
    const int ko = (kb + kt) * 32 + tc;
    if constexpr (ABF16) {
      const unsigned short* ap = Ab + ko;
#pragma unroll
      for (int i = 0; i < ITA; ++i)
        rg.rab[i] = *reinterpret_cast<const ushort4*>(ap + (size_t)(tr + 32 * i) * K);
    } else {
      const float* ap = Af + ko;
#pragma unroll
      for (int i = 0; i < ITA; ++i)
        rg.ra[i] = *reinterpret_cast<const f32x4*>(ap + (size_t)(tr + 32 * i) * K);
    }
    const float* wp = Wb + ko;
#pragma unroll
    for (int i = 0; i < 2; ++i)
      rg.rw[i] = *reinterpret_cast<const f32x4*>(wp + (size_t)(tr + 32 * i) * K);
  };

  auto storeT = [&](RS& rg, int bo) {
    unsigned short* sA = &lA[bo * MT * PITCH];
    unsigned short* sW = &lW[bo * 64 * PITCH];
#pragma unroll
    for (int i = 0; i < ITA; ++i) {
      ushort4 u;
      if constexpr (ABF16) u = rg.rab[i];
      else {
        f32x4 v = rg.ra[i];
        if (aact) { v[0]=fmaxf(v[0],0.f); v[1]=fmaxf(v[1],0.f);
                    v[2]=fmaxf(v[2],0.f); v[3]=fmaxf(v[3],0.f); }
        u.x = f2bf(v[0]); u.y = f2bf(v[1]); u.z = f2bf(v[2]); u.w = f2bf(v[3]);
      }
      *reinterpret_cast<ushort4*>(&sA[(tr + 32 * i) * PITCH + tc]) = u;
    }
#pragma unroll
    for (int i = 0; i < 2; ++i) {
      f32x4 v = rg.rw[i]; ushort4 u;
      u.x = f2bf(v[0]); u.y = f2bf(v[1]); u.z = f2bf(v[2]); u.w = f2bf(v[3]);
      *reinterpret_cast<ushort4*>(&sW[(tr + 32 * i) * PITCH + tc]) = u;
    }
  };

  auto comp = [&](int bo) {
    const unsigned short* sA = &lA[bo * MT * PITCH];
    const unsigned short* sW = &lW[bo * 64 * PITCH];
    bf16x8 af[MR], bfr[4];
#pragma unroll
    for (int m = 0; m < MR; ++m)
      af[m] = *reinterpret_cast<const bf16x8*>(&sA[(wv * WM + m * 16 + r16) * PITCH + k8]);
#pragma unroll
    for (int n = 0; n < 4; ++n)
      bfr[n] = *reinterpret_cast<const bf16x8*>(&sW[(n * 16 + r16) * PITCH + k8]);
#pragma unroll
    for (int m = 0; m < MR; ++m)
#pragma unroll
      for (int n = 0; n < 4; ++n)
        acc[m][n] = __builtin_amdgcn_mfma_f32_16x16x32_bf16(af[m], bfr[n], acc[m][n], 0, 0, 0);
  };

#define GB_BARRIER() do { \
    asm volatile("s_waitcnt lgkmcnt(0)" ::: "memory"); \
    __builtin_amdgcn_sched_barrier(0); \
    __builtin_amdgcn_s_barrier(); \
  } while (0)

  RS ra_, rb_;
  loadT(ra_, 0);
  loadT(rb_, 1);
  storeT(ra_, 0);
  GB_BARRIER();

  for (int kt = 0; kt < NK; kt += 2) {
    if (kt + 2 < NK) loadT(ra_, kt + 2);
    comp(0);
    storeT(rb_, 1);
    GB_BARRIER();
    if (kt + 3 < NK) loadT(rb_, kt + 3);
    comp(1);
    if (kt + 2 < NK) {
      storeT(ra_, 0);
      GB_BARRIER();
    }
  }
#undef GB_BARRIER

#pragma unroll
  for (int n = 0; n < 4; ++n) {
    const int col = n0 + n * 16 + r16;
    const float bv = (bias && nsplit == 1) ? bias[col] : 0.f;
#pragma unroll
    for (int m = 0; m < MR; ++m) {
      const int rbase = m0 + wv * WM + m * 16 + (lane >> 4) * 4;
#pragma unroll
      for (int r = 0; r < 4; ++r) {
        float v = acc[m][n][r] + bv;
        if (act) v = fmaxf(v, 0.f);
        if (nsplit > 1) {
          atomicAdd(&C[(size_t)(rbase + r) * ldc + col_off + col], v);
        } else {
          C[(size_t)(rbase + r) * ldc + col_off + col] = v;
        }
      }
    }
  }
}

// ---- prep: X0=[emb|h], X1=[emb|0]; bias-init alog/xact/gi/gh ---------------
__global__ void prep_kernel(const int* __restrict__ ids, const float* __restrict__ hid,
                            const float* __restrict__ emb,
                            const float* __restrict__ attn_b, const float* __restrict__ comb_b,
                            const float* __restrict__ b_ih, const float* __restrict__ b_hh,
                            float* __restrict__ X0, float* __restrict__ X1,
                            float* __restrict__ alog, float* __restrict__ xact,
                            float* __restrict__ gi, float* __restrict__ gh)
{
  const int b = blockIdx.x, t = threadIdx.x;
  const int row = ids[b];
  f32x4 e = *reinterpret_cast<const f32x4*>(emb + (size_t)row * Hdim + t * 4);
  *reinterpret_cast<f32x4*>(X0 + (size_t)b * 2048 + t * 4) = e;
  *reinterpret_cast<f32x4*>(X1 + (size_t)b * 2048 + t * 4) = e;
  f32x4 h = *reinterpret_cast<const f32x4*>(hid + (size_t)b * Hdim + t * 4);
  *reinterpret_cast<f32x4*>(X0 + (size_t)b * 2048 + 1024 + t * 4) = h;
  f32x4 z4 = {0.f, 0.f, 0.f, 0.f};
  *reinterpret_cast<f32x4*>(X1 + (size_t)b * 2048 + 1024 + t * 4) = z4;
  if (t < 128)
    *reinterpret_cast<f32x4*>(alog + (size_t)b * Ldim + t * 4) =
        *reinterpret_cast<const f32x4*>(attn_b + t * 4);
  *reinterpret_cast<f32x4*>(xact + (size_t)b * Hdim + t * 4) =
      *reinterpret_cast<const f32x4*>(comb_b + t * 4);
#pragma unroll
  for (int i = 0; i < 3; ++i) {
    *reinterpret_cast<f32x4*>(gi + (size_t)b * 3072 + i * 1024 + t * 4) =
        *reinterpret_cast<const f32x4*>(b_ih + i * 1024 + t * 4);
    *reinterpret_cast<f32x4*>(gh + (size_t)b * 3072 + i * 1024 + t * 4) =
        *reinterpret_cast<const f32x4*>(b_hh + i * 1024 + t * 4);
  }
}

// ---- encoder transpose: encT[h][l] = enc[l][h] -----------------------------
__global__ void transpose_kernel(const float* __restrict__ enc, float* __restrict__ encT)
{
  __shared__ float tile[64][65];
  const int l0 = blockIdx.x * 64, h0 = blockIdx.y * 64;
  const int t = threadIdx.x;
  const int c = t & 63, rr = t >> 6;
#pragma unroll
  for (int p = 0; p < 16; ++p) {
    const int r = p * 4 + rr;
    tile[r][c] = enc[(size_t)(l0 + r) * Hdim + h0 + c];
  }
  __syncthreads();
#pragma unroll
  for (int p = 0; p < 16; ++p) {
    const int r = p * 4 + rr;
    encT[(size_t)(h0 + r) * Ldim + l0 + c] = tile[c][r];
  }
}

// ---- softmax over L=512 per row --------------------------------------------
__global__ void attn_softmax_kernel(const float* __restrict__ logits, float* __restrict__ wout)
{
  __shared__ float red[256];
  const int b = blockIdx.x, t = threadIdx.x;
  const float x0 = logits[b * Ldim + t];
  const float x1 = logits[b * Ldim + 256 + t];
  red[t] = fmaxf(x0, x1); __syncthreads();
  for (int o = 128; o > 0; o >>= 1) { if (t < o) red[t] = fmaxf(red[t], red[t + o]); __syncthreads(); }
  const float m = red[0]; __syncthreads();
  const float e0 = __expf(x0 - m), e1 = __expf(x1 - m);
  red[t] = e0 + e1; __syncthreads();
  for (int o = 128; o > 0; o >>= 1) { if (t < o) red[t] += red[t + o]; __syncthreads(); }
  const float inv = 1.f / red[0];
  wout[b * Ldim + t]       = e0 * inv;
  wout[b * Ldim + 256 + t] = e1 * inv;
}

// ---- GRU pointwise ---------------------------------------------------------
DEVI float sigm(float x) { return 1.f / (1.f + __expf(-x)); }

__global__ void gru_kernel(const float* __restrict__ gi, const float* __restrict__ gh,
                           const float* __restrict__ hin,
                           float* __restrict__ hnew, unsigned short* __restrict__ hnbf)
{
  const int idx = blockIdx.x * 256 + threadIdx.x;
  const int b = idx >> 10, j = idx & 1023;
  const float* gib = gi + (size_t)b * 3072;
  const float* ghb = gh + (size_t)b * 3072;
  const float r = sigm(gib[j] + ghb[j]);
  const float z = sigm(gib[1024 + j] + ghb[1024 + j]);
  const float n = tanhf(gib[2048 + j] + r * ghb[2048 + j]);
  const float h = hin[idx];
  const float hn = (1.f - z) * n + z * h;
  hnew[idx] = hn;
  hnbf[idx] = f2bf(hn);
}

// ---- LSE: reduce per-block partials to lse[b] ------------------------------
__global__ void lse_reduce(const float2* __restrict__ part, int npart,
                           float* __restrict__ lse)
{
  __shared__ float rm[256], rs[256];
  const int b = blockIdx.x, t = threadIdx.x;
  float m = -1e30f, s = 0.f;
  for (int j = t; j < npart; j += 256) {
    const float2 p = part[(size_t)b * npart + j];
    const float nm = fmaxf(m, p.x);
    s = s * __expf(m - nm) + p.y * __expf(p.x - nm);
    m = nm;
  }
  rm[t] = m; rs[t] = s; __syncthreads();
  for (int o = 128; o > 0; o >>= 1) {
    if (t < o) {
      const float m2 = rm[t + o], s2 = rs[t + o];
      const float nm = fmaxf(rm[t], m2);
      rs[t] = rs[t] * __expf(rm[t] - nm) + s2 * __expf(m2 - nm);
      rm[t] = nm;
    }
    __syncthreads();
  }
  if (t == 0) lse[b] = rm[0] + __logf(rs[0]);
}

// ---- subtract lse in place (2048 blocks, full-BW streaming) ----------------
__global__ void lsm_sub(const float* __restrict__ lse, float* __restrict__ out)
{
  const int b = blockIdx.x >> 3, c = blockIdx.x & 7;
  const float l = lse[b];
  f32x4* row4 = reinterpret_cast<f32x4*>(out + (size_t)b * Vdim) + c * 1000;
  for (int i = threadIdx.x; i < 1000; i += 256) {
    f32x4 x = row4[i];
    x[0] -= l; x[1] -= l; x[2] -= l; x[3] -= l;
    row4[i] = x;
  }
}

// ---------------------------------------------------------------------------
extern "C" void kernel_launch(void* const* d_in, const int* in_sizes, int n_in,
                              void* d_out, int out_size, void* d_ws, size_t ws_size,
                              hipStream_t stream)
{
  (void)in_sizes; (void)n_in; (void)out_size; (void)ws_size;

  const int*   ids    = (const int*)  d_in[0];
  const float* hid    = (const float*)d_in[1];
  const float* enc    = (const float*)d_in[2];
  const float* emb    = (const float*)d_in[3];
  const float* attn_W = (const float*)d_in[4];
  const float* attn_b = (const float*)d_in[5];
  const float* comb_W = (const float*)d_in[6];
  const float* comb_b = (const float*)d_in[7];
  const float* W_ih   = (const float*)d_in[8];
  const float* W_hh   = (const float*)d_in[9];
  const float* b_ih   = (const float*)d_in[10];
  const float* b_hh   = (const float*)d_in[11];
  const float* out_W  = (const float*)d_in[12];
  const float* out_b  = (const float*)d_in[13];

  float* out_logits = (float*)d_out;                       // [B,V]
  float* out_h      = out_logits + (size_t)Bdim * Vdim;    // [B,H]
  float* out_attw   = out_h + (size_t)Bdim * Hdim;         // [B,L]

  char* w = (char*)d_ws;
  float* X0   = (float*)w; w += (size_t)Bdim * 2048 * 4;
  float* X1   = (float*)w; w += (size_t)Bdim * 2048 * 4;
  float* encT = (float*)w; w += (size_t)Hdim * Ldim * 4;
  float* alog = (float*)w; w += (size_t)Bdim * Ldim * 4;
  float* xact = (float*)w; w += (size_t)Bdim * Hdim * 4;
  float* gi   = (float*)w; w += (size_t)Bdim * 3 * Hdim * 4;
  float* gh   = (float*)w; w += (size_t)Bdim * 3 * Hdim * 4;
  unsigned short* hnbf = (unsigned short*)w; w += (size_t)Bdim * Hdim * 2;
  float2* plse = (float2*)w; w += (size_t)Bdim * (Vdim / 32) * 8;
  float* lse  = (float*)w; w += (size_t)Bdim * 4;

  prep_kernel<<<Bdim, 256, 0, stream>>>(ids, hid, emb, attn_b, comb_b, b_ih, b_hh,
                                        X0, X1, alog, xact, gi, gh);
  transpose_kernel<<<dim3(Ldim / 64, Hdim / 64), 256, 0, stream>>>(enc, encT);

  // attn logits [B,L] += X0 @ attn_W^T   (split-K=8, bias pre-init)
  gemm_bt<32, false, false><<<dim3(Ldim / 64, 2, 8), 256, 0, stream>>>(
      X0, attn_W, nullptr, nullptr, nullptr, alog, nullptr,
      2048, Ldim, 0, 0, 0, 8);
  attn_softmax_kernel<<<Bdim, 256, 0, stream>>>(alog, out_attw);

  // attn_applied [B,H] += attn_w @ encT^T -> X1 right half (split-K=4)
  gemm_bt<32, false, false><<<dim3(Hdim / 64, 2, 4), 256, 0, stream>>>(
      out_attw, encT, nullptr, nullptr, nullptr, X1, nullptr,
      512, 2048, 1024, 0, 0, 4);

  // xact [B,H] += X1 @ comb_W^T  (split-K=8; ReLU deferred to gi's A-staging)
  gemm_bt<32, false, false><<<dim3(Hdim / 64, 2, 8), 256, 0, stream>>>(
      X1, comb_W, nullptr, nullptr, nullptr, xact, nullptr,
      2048, Hdim, 0, 0, 0, 8);

  // gi += relu(xact) @ W_ih^T ; gh += h @ W_hh^T  (dual, split-K=4)
  gemm_bt<32, false, true><<<dim3(3 * Hdim / 64, 2, 8), 256, 0, stream>>>(
      xact, W_ih, hid, W_hh, nullptr, gi, gh,
      1024, 3 * Hdim, 0, 0, 1, 4);

  gru_kernel<<<Bdim * Hdim / 256, 256, 0, stream>>>(gi, gh, hid, out_h, hnbf);

  // logits [B,V] = h_new @ out_W^T + out_b  (bytes-minimal + depth-2 pipeline)
  gemm_flat5<<<Vdim / 128, 1024, 0, stream>>>(hnbf, out_W, out_b, out_logits, plse);

  lse_reduce<<<Bdim, 256, 0, stream>>>(plse, Vdim / 128, lse);
  lsm_sub<<<Bdim * 8, 256, 0, stream>>>(lse, out_logits);
}

// Round 8
// 115.551 us; speedup vs baseline: 1.7266x; 1.0557x over previous
//
#include <hip/hip_runtime.h>
#include <hip/hip_bf16.h>
#include <cstdint>

#define DEVI __device__ __forceinline__

typedef __bf16 bf16x8 __attribute__((ext_vector_type(8)));
typedef float  f32x4  __attribute__((ext_vector_type(4)));

constexpr int Hdim = 1024;
constexpr int Vdim = 32000;
constexpr int Ldim = 512;
constexpr int Bdim = 256;

DEVI unsigned short f2bf(float f) {
  __bf16 h = (__bf16)f;                       // RNE
  return __builtin_bit_cast(unsigned short, h);
}

// ===========================================================================
// gemm_flat5 (FROZEN, r7): C[256x32000] = A(bf16) @ W(f32)^T + bias.
// At the ~5.2 TB/s supply invariant: 292 MB traffic -> ~58 us. Ntile 128,
// grid 250, depth-2 pipeline, 4 LDS bufs, W read exactly once.
// ===========================================================================
constexpr int FP4 = 36;              // LDS row pitch in bf16 elems

__global__ __launch_bounds__(1024, 4)
void gemm_flat5(const unsigned short* __restrict__ A,
                const float* __restrict__ W,
                const float* __restrict__ bias,
                float* __restrict__ C,
                float2* __restrict__ plse)
{
  __shared__ unsigned short lW[4][128 * FP4];   // 4 x 9216 B = 36 KB

  const int t    = threadIdx.x;
  const int lane = t & 63;
  const int wv   = t >> 6;            // 0..15 -> M rows [wv*16, wv*16+16)
  const int r16  = lane & 15;
  const int k8   = (lane >> 4) * 8;
  const int n0   = blockIdx.x * 128;

  const int srow = t >> 3;            // staging row 0..127
  const int stc  = (t & 7) * 4;       // staging k-elem

  const float*          Wb = W + (size_t)(n0 + srow) * 1024 + stc;
  const unsigned short* Ab = A + (size_t)(wv * 16 + r16) * 1024 + k8;

  f32x4 acc[8];
#pragma unroll
  for (int n = 0; n < 8; ++n)
#pragma unroll
    for (int r = 0; r < 4; ++r) acc[n][r] = 0.f;

  f32x4 w0_, w1_;
  uint4 a0_, a1_, a2_, a3_;

#define LOADW(RW, KT) RW = *reinterpret_cast<const f32x4*>(Wb + (KT) * 32)
#define LOADA(RA, KT) RA = *reinterpret_cast<const uint4*>(Ab + (KT) * 32)

#define STOREW(RW, BUF) do {                                                   \
    ushort4 u_;                                                                \
    u_.x = f2bf(RW[0]); u_.y = f2bf(RW[1]);                                    \
    u_.z = f2bf(RW[2]); u_.w = f2bf(RW[3]);                                    \
    *reinterpret_cast<ushort4*>(&lW[BUF][srow * FP4 + stc]) = u_;              \
  } while (0)

#define COMP(RA, BUF) do {                                                     \
    _Pragma("unroll")                                                          \
    for (int n = 0; n < 8; ++n) {                                              \
      bf16x8 bw_ = *reinterpret_cast<const bf16x8*>(                           \
          &lW[BUF][(n * 16 + r16) * FP4 + k8]);                                \
      acc[n] = __builtin_amdgcn_mfma_f32_16x16x32_bf16(                        \
          __builtin_bit_cast(bf16x8, RA), bw_, acc[n], 0, 0, 0);               \
    }                                                                          \
  } while (0)

  LOADW(w0_, 0); LOADW(w1_, 1);
  LOADA(a0_, 0); LOADA(a1_, 1); LOADA(a2_, 2); LOADA(a3_, 3);
  STOREW(w0_, 0); LOADW(w0_, 2);
  STOREW(w1_, 1); LOADW(w1_, 3);
  __syncthreads();

  for (int kt = 0; kt < 32; kt += 4) {
    COMP(a0_, 0);
    STOREW(w0_, 2);
    { const int kn = (kt + 4 < 32) ? kt + 4 : 31; LOADW(w0_, kn); LOADA(a0_, kn); }
    __syncthreads();

    COMP(a1_, 1);
    STOREW(w1_, 3);
    { const int kn = (kt + 5 < 32) ? kt + 5 : 31; LOADW(w1_, kn); LOADA(a1_, kn); }
    __syncthreads();

    COMP(a2_, 2);
    STOREW(w0_, 0);
    { const int kn = (kt + 6 < 32) ? kt + 6 : 31; LOADW(w0_, kn); LOADA(a2_, kn); }
    __syncthreads();

    COMP(a3_, 3);
    STOREW(w1_, 1);
    { const int kn = (kt + 7 < 32) ? kt + 7 : 31; LOADW(w1_, kn); LOADA(a3_, kn); }
    __syncthreads();
  }

#undef COMP
#undef STOREW
#undef LOADA
#undef LOADW

#pragma unroll
  for (int n = 0; n < 8; ++n) {
    const int col = n0 + n * 16 + r16;
    const float bv = bias[col];
    const int rbase = wv * 16 + (lane >> 4) * 4;
#pragma unroll
    for (int r = 0; r < 4; ++r) {
      const float v = acc[n][r] + bv;
      acc[n][r] = v;
      C[(size_t)(rbase + r) * Vdim + col] = v;
    }
  }
#pragma unroll
  for (int r = 0; r < 4; ++r) {
    float mx = -1e30f;
#pragma unroll
    for (int n = 0; n < 8; ++n) mx = fmaxf(mx, acc[n][r]);
#pragma unroll
    for (int o = 1; o < 16; o <<= 1) mx = fmaxf(mx, __shfl_xor(mx, o, 16));
    float s = 0.f;
#pragma unroll
    for (int n = 0; n < 8; ++n) s += __expf(acc[n][r] - mx);
#pragma unroll
    for (int o = 1; o < 16; o <<= 1) s += __shfl_xor(s, o, 16);
    if (r16 == 0) {
      const int row = wv * 16 + (lane >> 4) * 4 + r;
      plse[(size_t)row * gridDim.x + blockIdx.x] = make_float2(mx, s);
    }
  }
}

// ===========================================================================
// gemm_multi: runtime-parameterized small-GEMM engine, TWO independent
// problems per dispatch (1D grid decode: id < n0blk -> q0, else q1).
// C[128x64 per block] += A[Mx K](f32) @ W[N x K](f32)^T via split-K
// atomicAdd (C pre-initialized with bias by prep). aact: ReLU A on staging.
// BTRANS: W is given ROW-MAJOR [K x N] (e.g. enc[L,H]); staged transposed.
// MFMA 16x16x32_bf16; C/D: col=lane&15, row=(lane>>4)*4+reg (m89-verified).
// NK per block must be even >= 2.
// ===========================================================================
struct GP {
  const float* A; const float* W; float* C;
  int K, ldc, ldb, col_off, aact, nsplit, gx;
};

template<bool BTRANS>
__global__ __launch_bounds__(256, 2)
void gemm_multi(GP q0, GP q1, int n0blk)
{
  constexpr int MT = 128, PITCH = 40, ITA = 4, MR = 2;

  __shared__ unsigned short lA[2 * MT * PITCH];
  __shared__ unsigned short lW[2 * 64 * PITCH];

  GP p = q0;
  int id = blockIdx.x;
  if (id >= n0blk) { p = q1; id -= n0blk; }
  const int bx  = id % p.gx;
  const int rem = id / p.gx;
  const int by  = rem & 1;
  const int kz  = rem >> 1;

  const int m0 = by * MT;
  const int n0 = bx * 64;
  const int NK = p.K / (32 * p.nsplit);
  const int kb = kz * NK;

  const int t  = threadIdx.x;
  const int tr = t >> 3;          // 0..31
  const int tc = (t & 7) * 4;

  const float* Af = p.A + (size_t)m0 * p.K;

  const int lane = t & 63;
  const int wv   = t >> 6;
  const int r16  = lane & 15;
  const int k8   = (lane >> 4) * 8;

  f32x4 acc[MR][4];
#pragma unroll
  for (int m = 0; m < MR; ++m)
#pragma unroll
    for (int n = 0; n < 4; ++n)
#pragma unroll
      for (int r = 0; r < 4; ++r) acc[m][n][r] = 0.f;

  struct RS { f32x4 ra[ITA]; f32x4 rw[2]; };

  auto loadT = [&](RS& rg, int kt) {
    const int ko = (kb + kt) * 32;
#pragma unroll
    for (int i = 0; i < ITA; ++i)
      rg.ra[i] = *reinterpret_cast<const f32x4*>(
          Af + (size_t)(tr + 32 * i) * p.K + ko + tc);
    if constexpr (BTRANS) {
      // W row-major [K x N]: read row l = ko+tr, cols n0+(t&7)*8 .. +8
      const float* wp = p.W + (size_t)(ko + tr) * p.ldb + n0 + (t & 7) * 8;
      rg.rw[0] = *reinterpret_cast<const f32x4*>(wp);
      rg.rw[1] = *reinterpret_cast<const f32x4*>(wp + 4);
    } else {
#pragma unroll
      for (int i = 0; i < 2; ++i)
        rg.rw[i] = *reinterpret_cast<const f32x4*>(
            p.W + (size_t)(n0 + tr + 32 * i) * p.ldb + ko + tc);
    }
  };

  auto storeT = [&](RS& rg, int bo) {
    unsigned short* sA = &lA[bo * MT * PITCH];
    unsigned short* sW = &lW[bo * 64 * PITCH];
#pragma unroll
    for (int i = 0; i < ITA; ++i) {
      f32x4 v = rg.ra[i];
      if (p.aact) { v[0]=fmaxf(v[0],0.f); v[1]=fmaxf(v[1],0.f);
                    v[2]=fmaxf(v[2],0.f); v[3]=fmaxf(v[3],0.f); }
      ushort4 u;
      u.x = f2bf(v[0]); u.y = f2bf(v[1]); u.z = f2bf(v[2]); u.w = f2bf(v[3]);
      *reinterpret_cast<ushort4*>(&sA[(tr + 32 * i) * PITCH + tc]) = u;
    }
    if constexpr (BTRANS) {
      const int hb = (t & 7) * 8;
#pragma unroll
      for (int j = 0; j < 4; ++j) {
        sW[(hb + j)     * PITCH + tr] = f2bf(rg.rw[0][j]);
        sW[(hb + 4 + j) * PITCH + tr] = f2bf(rg.rw[1][j]);
      }
    } else {
#pragma unroll
      for (int i = 0; i < 2; ++i) {
        f32x4 v = rg.rw[i]; ushort4 u;
        u.x = f2bf(v[0]); u.y = f2bf(v[1]); u.z = f2bf(v[2]); u.w = f2bf(v[3]);
        *reinterpret_cast<ushort4*>(&sW[(tr + 32 * i) * PITCH + tc]) = u;
      }
    }
  };

  auto comp = [&](int bo) {
    const unsigned short* sA = &lA[bo * MT * PITCH];
    const unsigned short* sW = &lW[bo * 64 * PITCH];
    bf16x8 af[MR], bfr[4];
#pragma unroll
    for (int m = 0; m < MR; ++m)
      af[m] = *reinterpret_cast<const bf16x8*>(&sA[(wv * 32 + m * 16 + r16) * PITCH + k8]);
#pragma unroll
    for (int n = 0; n < 4; ++n)
      bfr[n] = *reinterpret_cast<const bf16x8*>(&sW[(n * 16 + r16) * PITCH + k8]);
#pragma unroll
    for (int m = 0; m < MR; ++m)
#pragma unroll
      for (int n = 0; n < 4; ++n)
        acc[m][n] = __builtin_amdgcn_mfma_f32_16x16x32_bf16(af[m], bfr[n], acc[m][n], 0, 0, 0);
  };

#define GB_BARRIER() do { \
    asm volatile("s_waitcnt lgkmcnt(0)" ::: "memory"); \
    __builtin_amdgcn_sched_barrier(0); \
    __builtin_amdgcn_s_barrier(); \
  } while (0)

  RS ra_, rb_;
  loadT(ra_, 0);
  loadT(rb_, 1);
  storeT(ra_, 0);
  GB_BARRIER();

  for (int kt = 0; kt < NK; kt += 2) {
    if (kt + 2 < NK) loadT(ra_, kt + 2);
    comp(0);
    storeT(rb_, 1);
    GB_BARRIER();
    if (kt + 3 < NK) loadT(rb_, kt + 3);
    comp(1);
    if (kt + 2 < NK) {
      storeT(ra_, 0);
      GB_BARRIER();
    }
  }
#undef GB_BARRIER

#pragma unroll
  for (int n = 0; n < 4; ++n) {
    const int col = n0 + n * 16 + r16;
#pragma unroll
    for (int m = 0; m < MR; ++m) {
      const int rbase = m0 + wv * 32 + m * 16 + (lane >> 4) * 4;
#pragma unroll
      for (int r = 0; r < 4; ++r)
        atomicAdd(&p.C[(size_t)(rbase + r) * p.ldc + p.col_off + col],
                  acc[m][n][r]);
    }
  }
}

// ---- prep: X0=[emb|h], X1=[emb|0]; bias-init alog/xact/gi/gh ---------------
__global__ void prep_kernel(const int* __restrict__ ids, const float* __restrict__ hid,
                            const float* __restrict__ emb,
                            const float* __restrict__ attn_b, const float* __restrict__ comb_b,
                            const float* __restrict__ b_ih, const float* __restrict__ b_hh,
                            float* __restrict__ X0, float* __restrict__ X1,
                            float* __restrict__ alog, float* __restrict__ xact,
                            float* __restrict__ gi, float* __restrict__ gh)
{
  const int b = blockIdx.x, t = threadIdx.x;
  const int row = ids[b];
  f32x4 e = *reinterpret_cast<const f32x4*>(emb + (size_t)row * Hdim + t * 4);
  *reinterpret_cast<f32x4*>(X0 + (size_t)b * 2048 + t * 4) = e;
  *reinterpret_cast<f32x4*>(X1 + (size_t)b * 2048 + t * 4) = e;
  f32x4 h = *reinterpret_cast<const f32x4*>(hid + (size_t)b * Hdim + t * 4);
  *reinterpret_cast<f32x4*>(X0 + (size_t)b * 2048 + 1024 + t * 4) = h;
  f32x4 z4 = {0.f, 0.f, 0.f, 0.f};
  *reinterpret_cast<f32x4*>(X1 + (size_t)b * 2048 + 1024 + t * 4) = z4;
  if (t < 128)
    *reinterpret_cast<f32x4*>(alog + (size_t)b * Ldim + t * 4) =
        *reinterpret_cast<const f32x4*>(attn_b + t * 4);
  *reinterpret_cast<f32x4*>(xact + (size_t)b * Hdim + t * 4) =
      *reinterpret_cast<const f32x4*>(comb_b + t * 4);
#pragma unroll
  for (int i = 0; i < 3; ++i) {
    *reinterpret_cast<f32x4*>(gi + (size_t)b * 3072 + i * 1024 + t * 4) =
        *reinterpret_cast<const f32x4*>(b_ih + i * 1024 + t * 4);
    *reinterpret_cast<f32x4*>(gh + (size_t)b * 3072 + i * 1024 + t * 4) =
        *reinterpret_cast<const f32x4*>(b_hh + i * 1024 + t * 4);
  }
}

// ---- softmax over L=512 per row --------------------------------------------
__global__ void attn_softmax_kernel(const float* __restrict__ logits, float* __restrict__ wout)
{
  __shared__ float red[256];
  const int b = blockIdx.x, t = threadIdx.x;
  const float x0 = logits[b * Ldim + t];
  const float x1 = logits[b * Ldim + 256 + t];
  red[t] = fmaxf(x0, x1); __syncthreads();
  for (int o = 128; o > 0; o >>= 1) { if (t < o) red[t] = fmaxf(red[t], red[t + o]); __syncthreads(); }
  const float m = red[0]; __syncthreads();
  const float e0 = __expf(x0 - m), e1 = __expf(x1 - m);
  red[t] = e0 + e1; __syncthreads();
  for (int o = 128; o > 0; o >>= 1) { if (t < o) red[t] += red[t + o]; __syncthreads(); }
  const float inv = 1.f / red[0];
  wout[b * Ldim + t]       = e0 * inv;
  wout[b * Ldim + 256 + t] = e1 * inv;
}

// ---- GRU pointwise ---------------------------------------------------------
DEVI float sigm(float x) { return 1.f / (1.f + __expf(-x)); }

__global__ void gru_kernel(const float* __restrict__ gi, const float* __restrict__ gh,
                           const float* __restrict__ hin,
                           float* __restrict__ hnew, unsigned short* __restrict__ hnbf)
{
  const int idx = blockIdx.x * 256 + threadIdx.x;
  const int b = idx >> 10, j = idx & 1023;
  const float* gib = gi + (size_t)b * 3072;
  const float* ghb = gh + (size_t)b * 3072;
  const float r = sigm(gib[j] + ghb[j]);
  const float z = sigm(gib[1024 + j] + ghb[1024 + j]);
  const float n = tanhf(gib[2048 + j] + r * ghb[2048 + j]);
  const float h = hin[idx];
  const float hn = (1.f - z) * n + z * h;
  hnew[idx] = hn;
  hnbf[idx] = f2bf(hn);
}

// ---- fused: per-block LSE recompute + subtract slice in place --------------
__global__ void lsm_sub2(const float2* __restrict__ part, int npart,
                         float* __restrict__ out)
{
  __shared__ float rm[256], rs[256];
  const int b = blockIdx.x >> 3, c = blockIdx.x & 7;
  const int t = threadIdx.x;
  float m = -1e30f, s = 0.f;
  for (int j = t; j < npart; j += 256) {
    const float2 p = part[(size_t)b * npart + j];
    const float nm = fmaxf(m, p.x);
    s = s * __expf(m - nm) + p.y * __expf(p.x - nm);
    m = nm;
  }
  rm[t] = m; rs[t] = s; __syncthreads();
  for (int o = 128; o > 0; o >>= 1) {
    if (t < o) {
      const float m2 = rm[t + o], s2 = rs[t + o];
      const float nm = fmaxf(rm[t], m2);
      rs[t] = rs[t] * __expf(rm[t] - nm) + s2 * __expf(m2 - nm);
      rm[t] = nm;
    }
    __syncthreads();
  }
  const float lse = rm[0] + __logf(rs[0]);
  f32x4* row4 = reinterpret_cast<f32x4*>(out + (size_t)b * Vdim) + c * 1000;
  for (int i = t; i < 1000; i += 256) {
    f32x4 x = row4[i];
    x[0] -= lse; x[1] -= lse; x[2] -= lse; x[3] -= lse;
    row4[i] = x;
  }
}

// ---------------------------------------------------------------------------
extern "C" void kernel_launch(void* const* d_in, const int* in_sizes, int n_in,
                              void* d_out, int out_size, void* d_ws, size_t ws_size,
                              hipStream_t stream)
{
  (void)in_sizes; (void)n_in; (void)out_size; (void)ws_size;

  const int*   ids    = (const int*)  d_in[0];
  const float* hid    = (const float*)d_in[1];
  const float* enc    = (const float*)d_in[2];
  const float* emb    = (const float*)d_in[3];
  const float* attn_W = (const float*)d_in[4];
  const float* attn_b = (const float*)d_in[5];
  const float* comb_W = (const float*)d_in[6];
  const float* comb_b = (const float*)d_in[7];
  const float* W_ih   = (const float*)d_in[8];
  const float* W_hh   = (const float*)d_in[9];
  const float* b_ih   = (const float*)d_in[10];
  const float* b_hh   = (const float*)d_in[11];
  const float* out_W  = (const float*)d_in[12];
  const float* out_b  = (const float*)d_in[13];

  float* out_logits = (float*)d_out;                       // [B,V]
  float* out_h      = out_logits + (size_t)Bdim * Vdim;    // [B,H]
  float* out_attw   = out_h + (size_t)Bdim * Hdim;         // [B,L]

  char* w = (char*)d_ws;
  float* X0   = (float*)w; w += (size_t)Bdim * 2048 * 4;
  float* X1   = (float*)w; w += (size_t)Bdim * 2048 * 4;
  float* alog = (float*)w; w += (size_t)Bdim * Ldim * 4;
  float* xact = (float*)w; w += (size_t)Bdim * Hdim * 4;
  float* gi   = (float*)w; w += (size_t)Bdim * 3 * Hdim * 4;
  float* gh   = (float*)w; w += (size_t)Bdim * 3 * Hdim * 4;
  unsigned short* hnbf = (unsigned short*)w; w += (size_t)Bdim * Hdim * 2;
  float2* plse = (float2*)w; w += (size_t)Bdim * (Vdim / 128) * 8;

  prep_kernel<<<Bdim, 256, 0, stream>>>(ids, hid, emb, attn_b, comb_b, b_ih, b_hh,
                                        X0, X1, alog, xact, gi, gh);

  // D1: attn logits [B,L] += X0 @ attn_W^T  AND  gh += h @ W_hh^T (independent)
  {
    GP p0 = { X0,  attn_W, alog, 2048, Ldim,     2048, 0, 0, 8,  Ldim / 64 };
    GP p1 = { hid, W_hh,   gh,   1024, 3 * Hdim, 1024, 0, 0, 4,  3 * Hdim / 64 };
    const int n0blk = p0.gx * 2 * p0.nsplit;                 // 128
    const int nblk  = n0blk + p1.gx * 2 * p1.nsplit;         // 128 + 384
    gemm_multi<false><<<nblk, 256, 0, stream>>>(p0, p1, n0blk);
  }

  attn_softmax_kernel<<<Bdim, 256, 0, stream>>>(alog, out_attw);

  // D2: attn_applied -> X1 right half: attn_w @ enc (enc transposed on stage)
  {
    GP p0 = { out_attw, enc, X1, 512, 2048, Hdim, 1024, 0, 4, Hdim / 64 };
    const int nblk = p0.gx * 2 * p0.nsplit;                  // 128
    gemm_multi<true><<<nblk, 256, 0, stream>>>(p0, p0, nblk);
  }

  // D3: xact += X1 @ comb_W^T   (ReLU deferred to D4's A-staging)
  {
    GP p0 = { X1, comb_W, xact, 2048, Hdim, 2048, 0, 0, 8, Hdim / 64 };
    const int nblk = p0.gx * 2 * p0.nsplit;                  // 256
    gemm_multi<false><<<nblk, 256, 0, stream>>>(p0, p0, nblk);
  }

  // D4: gi += relu(xact) @ W_ih^T
  {
    GP p0 = { xact, W_ih, gi, 1024, 3 * Hdim, 1024, 0, 1, 4, 3 * Hdim / 64 };
    const int nblk = p0.gx * 2 * p0.nsplit;                  // 384
    gemm_multi<false><<<nblk, 256, 0, stream>>>(p0, p0, nblk);
  }

  gru_kernel<<<Bdim * Hdim / 256, 256, 0, stream>>>(gi, gh, hid, out_h, hnbf);

  // logits [B,V] = h_new @ out_W^T + out_b  (frozen flat5)
  gemm_flat5<<<Vdim / 128, 1024, 0, stream>>>(hnbf, out_W, out_b, out_logits, plse);

  // fused LSE recompute + in-place subtract
  lsm_sub2<<<Bdim * 8, 256, 0, stream>>>(plse, Vdim / 128, out_logits);
}